// Round 8
// baseline (588.400 us; speedup 1.0000x reference)
//
#include <hip/hip_runtime.h>

#define C 10

typedef float f4_t __attribute__((ext_vector_type(4)));
typedef float f2_t __attribute__((ext_vector_type(2)));

__device__ __forceinline__ float waveSum(float v) {
#pragma unroll
  for (int o = 32; o > 0; o >>= 1) v += __shfl_down(v, o, 64);
  return v;
}
__device__ __forceinline__ float waveMin(float v) {
#pragma unroll
  for (int o = 32; o > 0; o >>= 1) v = fminf(v, __shfl_down(v, o, 64));
  return v;
}
__device__ __forceinline__ float waveMax(float v) {
#pragma unroll
  for (int o = 32; o > 0; o >>= 1) v = fmaxf(v, __shfl_down(v, o, 64));
  return v;
}
__device__ __forceinline__ unsigned waveMaxU(unsigned v) {
#pragma unroll
  for (int o = 32; o > 0; o >>= 1) {
    unsigned w = (unsigned)__shfl_down((int)v, o, 64);
    v = v > w ? v : w;
  }
  return v;
}

// ---------------- pass 1: NO-LDS direct-row streaming.
// Round-7 lesson: depth-2 prefetch at 16 waves/CU == depth-1 at 16 waves/CU
// (total 376.5 vs 379.4) -> pass1 is resident-wave-limited, not per-wave-
// depth-limited. This version deletes the LDS transpose entirely: each lane
// NT-loads its own 2 rows (5 contiguous float4; 80-B stride across lanes --
// the wave's 5 loads cover the same 40 cache lines a coalesced pattern
// would, zero wasted bytes). No LDS round-trip serialization, ONE __logf
// per element (was 2), ~55 live VGPR -> fits launch_bounds(128,8)'s
// 64-VGPR target WITHOUT spill -> 32 waves/CU of pure TLP.
// GATES: VGPR<=64, WRITE_SIZE~17MB. Round-1's spill disaster was a 40-reg
// prefetch body under a 32-reg cap; this body is genuinely small.
__global__ __launch_bounds__(128, 8) void pass1(
    const float4* __restrict__ probs4, const float4* __restrict__ y4,
    float2* __restrict__ us2,
    unsigned* __restrict__ uminInvSlots, unsigned* __restrict__ umaxSlots,
    float* __restrict__ ceSlots, float* __restrict__ focalSlots,
    int npairs) {
  const int t = blockIdx.x * 128 + threadIdx.x;
  const int T = gridDim.x * 128;
  const int lane = threadIdx.x & 63;
  const f4_t* bp = (const f4_t*)probs4;
  const f4_t* by = (const f4_t*)y4;

  // label0 = argmax of flattened y == label of sample 0 (first max). L2-hot.
  int label0 = 0;
  {
    const float* yf = (const float*)y4;
    float m = yf[0];
#pragma unroll
    for (int c = 1; c < C; ++c) {
      float v = yf[c];
      if (v > m) { m = v; label0 = c; }
    }
  }

  float ceA = 0.f, foA = 0.f;
  float mnA = __uint_as_float(0x7f800000u), mxA = 0.f;

  for (int pi = t; pi < npairs; pi += T) {
    // One pair = 2 samples = 20 floats = 5 float4, lane-contiguous.
    f4_t P[5], Y[5];
    const f4_t* gp = bp + (size_t)pi * 5;
    const f4_t* gy = by + (size_t)pi * 5;
#pragma unroll
    for (int q = 0; q < 5; ++q) {
      P[q] = __builtin_nontemporal_load(gp + q);
      Y[q] = __builtin_nontemporal_load(gy + q);
    }

    float u0 = 0.f, u1 = 0.f;
    float m0 = -1.f, m1 = -1.f;  // probs >= 0
    int am0 = 0, am1 = 0;
#pragma unroll
    for (int q = 0; q < 5; ++q) {
      float pv[4] = {P[q].x, P[q].y, P[q].z, P[q].w};
      float yv[4] = {Y[q].x, Y[q].y, Y[q].z, Y[q].w};
#pragma unroll
      for (int j = 0; j < 4; ++j) {
        const int e = 4 * q + j;  // 0..19, compile-time after unroll
        float p = pv[j];
        float lp = __logf(fmaxf(p, 1e-10f));           // shared: entropy + ce
        float te = yv[j] * fmaxf(lp, -18.420681f);     // y * log(max(p,1e-8))
        ceA -= te;
        foA -= te * (1.f - p);
        if (e < 10) {
          u0 -= p * lp;
          if (p > m0) { m0 = p; am0 = e; }             // strict > = first max
        } else {
          u1 -= p * lp;
          if (p > m1) { m1 = p; am1 = e - 10; }
        }
      }
    }
    mnA = fminf(mnA, fminf(u0, u1));
    mxA = fmaxf(mxA, fmaxf(u0, u1));

    // pack acc into sign bit (unc >= 0; sign set == inaccurate)
    unsigned s0 = __float_as_uint(u0) | ((am0 == label0) ? 0u : 0x80000000u);
    unsigned s1 = __float_as_uint(u1) | ((am1 == label0) ? 0u : 0x80000000u);
    f2_t o;
    o.x = __uint_as_float(s0);
    o.y = __uint_as_float(s1);
    __builtin_nontemporal_store(o, (f2_t*)&us2[pi]);   // coalesced f2 store
  }

  // per-wave reduce + spread-slot atomics.
  float ce = waveSum(ceA), fo = waveSum(foA);
  float mn = waveMin(mnA), mx = waveMax(mxA);
  if (lane == 0) {
    int slot = (t >> 6) & 63;
    atomicAdd(&ceSlots[slot], ce);
    atomicAdd(&focalSlots[slot], fo);
    atomicMax(&uminInvSlots[slot], ~__float_as_uint(mn));  // min via ~bits
    atomicMax(&umaxSlots[slot], __float_as_uint(mx));
  }
}

// ---------------- pass 2: 22-bin x 4-category histogram. grid 1024 = exactly
// 4 iterations/thread. NO done-counter / fused finale (round-3 regression:
// serialized same-address cross-XCD atomics). NT load on us. UNCHANGED from
// round 7 (single-variable discipline).
__global__ __launch_bounds__(256, 4) void pass2(
    const float4* __restrict__ us4, int n4,
    const unsigned* __restrict__ uminInvSlots, const unsigned* __restrict__ umaxSlots,
    float* __restrict__ ghist) {
  __shared__ float hist[88 * 64];  // [row][lane], 22528 B
  __shared__ float smm[2];
  const int tid = threadIdx.x, lane = tid & 63;
  for (int i = tid; i < 88 * 64; i += 256) hist[i] = 0.f;
  if (tid < 64) {
    unsigned mnInv = waveMaxU(uminInvSlots[tid]);
    unsigned mxb = waveMaxU(umaxSlots[tid]);
    if (tid == 0) { smm[0] = __uint_as_float(~mnInv); smm[1] = __uint_as_float(mxb); }
  }
  __syncthreads();
  const float umin = smm[0], delta = smm[1] - smm[0];
  float th[21];
#pragma unroll
  for (int k = 0; k < 21; ++k) th[k] = fmaf(0.05f * (float)k, delta, umin);

  const int stride = gridDim.x * 256;
  for (int i = blockIdx.x * 256 + tid; i < n4; i += stride) {
    f4_t v = __builtin_nontemporal_load((const f4_t*)us4 + i);
    float vv[4] = {v.x, v.y, v.z, v.w};
#pragma unroll
    for (int q = 0; q < 4; ++q) {
      unsigned b = __float_as_uint(vv[q]);
      int rb = (b >> 31) ? 44 : 0;  // acc rows 0..43, inacc rows 44..87
      float u = __uint_as_float(b & 0x7fffffffu);
      float e = u * 0.4342944819f;  // u / ln(10)
      float lnum = __logf(e * 0.9f);
      float lden = __logf(fmaxf((1.f - e) * 0.1f, 1e-10f));
      float x = fmaxf(lnum - lden, -23.0258509f) * 100.f;
      float s = __builtin_amdgcn_rcpf(1.f + __expf(-x));                   // sigmoid
      float t = 1.f - 2.f * __builtin_amdgcn_rcpf(__expf(2.f * u) + 1.f);  // tanh
      float wc = (1.f - s) * (1.f - t), wu = s * t;
      int j = 0;  // j = #{k: u > th_k}; le[k] <=> k >= j
#pragma unroll
      for (int k = 0; k < 21; ++k) j += (u > th[k]) ? 1 : 0;
      atomicAdd(&hist[(rb + j) * 64 + lane], wc);        // ds_add_f32
      atomicAdd(&hist[(rb + 22 + j) * 64 + lane], wu);
    }
  }
  __syncthreads();
  // tree-reduce 64 columns per row
#pragma unroll
  for (int st = 32; st >= 1; st >>= 1) {
    for (int idx = tid; idx < 88 * st; idx += 256) {
      int r = idx / st, c = idx - r * st;
      hist[r * 64 + c] += hist[r * 64 + c + st];
    }
    __syncthreads();
  }
  int slot = blockIdx.x & 63;
  for (int r = tid; r < 88; r += 256)
    atomicAdd(&ghist[slot * 88 + r], hist[r * 64]);
}

// ---------------- pass 3: reduce 64 slot-copies + scalar slots, emit outputs
__global__ __launch_bounds__(256) void pass3(
    const float* __restrict__ ghist,
    const float* __restrict__ ceSlots, const float* __restrict__ focalSlots,
    float* __restrict__ out, float invN) {
  __shared__ float hr[96];
  __shared__ float scf[2];
  int tid = threadIdx.x;
  if (tid < 88) {
    float s = 0.f;
    for (int q = 0; q < 64; ++q) s += ghist[q * 88 + tid];  // coalesced across tid
    hr[tid] = s;
  }
  if (tid >= 128 && tid < 192) {
    int l = tid - 128;
    float ce = waveSum(ceSlots[l]);
    float fo = waveSum(focalSlots[l]);
    if (l == 0) { scf[0] = ce; scf[1] = fo; }
  }
  __syncthreads();
  if (tid == 0) {
    // Running sums straight from LDS (low-VGPR finale).
    float totAU = 0.f, totIU = 0.f;
    for (int j = 0; j < 22; ++j) { totAU += hr[22 + j]; totIU += hr[66 + j]; }
    float n_ac = 0.f, n_ic = 0.f, n_au = totAU, n_iu = totIU;
    float auc = 0.f, prev = 0.f;
    for (int k = 0; k < 21; ++k) {
      n_ac += hr[k]; n_ic += hr[44 + k];
      n_au -= hr[22 + k]; n_iu -= hr[66 + k];
      float avu = (n_ac + n_iu) / (n_ac + n_au + n_ic + n_iu + 1e-10f);
      if (k > 0) auc += (avu + prev) * 0.5f * 0.05f;
      prev = avu;
    }
    out[0] = -logf(fmaxf(auc, 1e-10f)) + scf[1] * invN;
    out[1] = scf[0] * invN;
  }
}

extern "C" void kernel_launch(void* const* d_in, const int* in_sizes, int n_in,
                              void* d_out, int out_size, void* d_ws, size_t ws_size,
                              hipStream_t stream) {
  const float* probs = (const float*)d_in[0];
  const float* y = (const float*)d_in[1];
  float* out = (float*)d_out;
  const int N = in_sizes[0] / C;

  // ws layout (floats): [0,64) uminInv slots, [64,128) umax slots,
  // [128,192) ce slots, [192,256) focal slots, [256,5888) ghist[64][88],
  // [5888, 5888+N) us
  float* wsf = (float*)d_ws;
  unsigned* uminInvSlots = (unsigned*)wsf;
  unsigned* umaxSlots = (unsigned*)(wsf + 64);
  float* ceSlots = wsf + 128;
  float* focalSlots = wsf + 192;
  float* ghist = wsf + 256;
  float* us = wsf + 5888;

  hipMemsetAsync(d_ws, 0, 5888 * sizeof(float), stream);  // accumulators -> 0

  const int npairs = N / 2;  // 2097152; 4 pairs/thread at 524288 threads
  float invN = 1.0f / (float)N;

  pass1<<<4096, 128, 0, stream>>>((const float4*)probs, (const float4*)y,
                                  (float2*)us, uminInvSlots, umaxSlots,
                                  ceSlots, focalSlots, npairs);
  pass2<<<1024, 256, 0, stream>>>((const float4*)us, N / 4, uminInvSlots,
                                  umaxSlots, ghist);
  pass3<<<1, 256, 0, stream>>>(ghist, ceSlots, focalSlots, out, invN);
}

// Round 9
// 379.978 us; speedup vs baseline: 1.5485x; 1.5485x over previous
//
#include <hip/hip_runtime.h>

#define C 10
#define CHUNK_ROWS 128
#define CHUNK_FLOATS 1280   // 128 rows * 10
#define CHUNK_F4 320        // float4s per chunk

typedef float f4_t __attribute__((ext_vector_type(4)));
typedef float f2_t __attribute__((ext_vector_type(2)));

__device__ __forceinline__ float waveSum(float v) {
#pragma unroll
  for (int o = 32; o > 0; o >>= 1) v += __shfl_down(v, o, 64);
  return v;
}
__device__ __forceinline__ float waveMin(float v) {
#pragma unroll
  for (int o = 32; o > 0; o >>= 1) v = fminf(v, __shfl_down(v, o, 64));
  return v;
}
__device__ __forceinline__ float waveMax(float v) {
#pragma unroll
  for (int o = 32; o > 0; o >>= 1) v = fmaxf(v, __shfl_down(v, o, 64));
  return v;
}
__device__ __forceinline__ unsigned waveMaxU(unsigned v) {
#pragma unroll
  for (int o = 32; o > 0; o >>= 1) {
    unsigned w = (unsigned)__shfl_down((int)v, o, 64);
    v = v > w ? v : w;
  }
  return v;
}

// ---------------- pass 1: SINGLE-WAVE blocks, coalesced-NT + LDS transpose.
// Evidence chain: depth-1(16 waves/CU)=depth-2(16 waves/CU) -> wave-limited,
// not depth-limited (r4 vs r7). Direct-row NT overfetches 1.56x (r8 FETCH
// 696MB) -> coalesced-per-instruction NT + LDS staging is the only clean
// pattern. Occupancy never exceeded ~36% with 2-wave blocks; this round
// isolates block granularity: 64-thread blocks, 5120 B LDS slice ->
// LDS limit 32 blocks/CU, VGPR 56 -> 8 waves/SIMD, grid 8192 = 32/CU.
// launch_bounds(64,4): ceiling 128 VGPR, no forced-32 pathology ((128,8)
// gave VGPR=32 twice: r1, r8), no spill risk for this 56-reg body.
__global__ __launch_bounds__(64, 4) void pass1(
    const float4* __restrict__ probs4, const float4* __restrict__ y4,
    float2* __restrict__ us2,
    unsigned* __restrict__ uminInvSlots, unsigned* __restrict__ umaxSlots,
    float* __restrict__ ceSlots, float* __restrict__ focalSlots,
    int nchunks) {
  __shared__ float lds[CHUNK_FLOATS];  // one wave's p tile: 5120 B
  const int lane = threadIdx.x;        // 0..63
  f4_t* const bufP = (f4_t*)lds;
  const f4_t* bp = (const f4_t*)probs4;
  const f4_t* by = (const f4_t*)y4;

  const int gw = blockIdx.x;   // one wave per block
  const int NW = gridDim.x;

  // label0 = argmax of flattened y == label of sample 0 (first max). L2-hot.
  int label0 = 0;
  {
    const float* yf = (const float*)y4;
    float m = yf[0];
#pragma unroll
    for (int c = 1; c < C; ++c) {
      float v = yf[c];
      if (v > m) { m = v; label0 = c; }
    }
  }

  f4_t P[5], Y[5];
  auto issue = [&](int c) {
    const f4_t* gp = bp + (size_t)c * CHUNK_F4 + lane;
    const f4_t* gy = by + (size_t)c * CHUNK_F4 + lane;
#pragma unroll
    for (int q = 0; q < 5; ++q) {
      P[q] = __builtin_nontemporal_load(gp + q * 64);   // coalesced 16B/lane
      Y[q] = __builtin_nontemporal_load(gy + q * 64);
    }
  };

  float ceA = 0.f, foA = 0.f;
  float mnA = __uint_as_float(0x7f800000u), mxA = 0.f;

  if (gw < nchunks) issue(gw);
  for (int c = gw; c < nchunks; c += NW) {
    // ---- elementwise phase (coalesced): logs for ce/focal, stage p to LDS.
#pragma unroll
    for (int q = 0; q < 5; ++q) {
      f4_t pv = P[q], yv = Y[q];
      float lpx = __logf(fmaxf(pv.x, 1e-10f));
      float lpy = __logf(fmaxf(pv.y, 1e-10f));
      float lpz = __logf(fmaxf(pv.z, 1e-10f));
      float lpw = __logf(fmaxf(pv.w, 1e-10f));
      // lp8 = log(max(p,1e-8)) == max(lp, log(1e-8))
      float tx = yv.x * fmaxf(lpx, -18.420681f);
      float ty = yv.y * fmaxf(lpy, -18.420681f);
      float tz = yv.z * fmaxf(lpz, -18.420681f);
      float tw = yv.w * fmaxf(lpw, -18.420681f);
      ceA -= tx + ty + tz + tw;
      foA -= tx * (1.f - pv.x) + ty * (1.f - pv.y) + tz * (1.f - pv.z) +
             tw * (1.f - pv.w);
      bufP[q * 64 + lane] = pv;
    }

    // ---- prefetch next chunk into dead P/Y regs (in flight through row
    // phase; per-register scoreboard waits).
    if (c + NW < nchunks) issue(c + NW);

    // ---- row phase: lane owns rows 2*lane, 2*lane+1 (5 float4 = 20 elems).
    float u0 = 0.f, u1 = 0.f;
    float m0 = -1.f, m1 = -1.f;
    int am0 = 0, am1 = 0;
#pragma unroll
    for (int q = 0; q < 5; ++q) {
      f4_t v = bufP[lane * 5 + q];
      float vv[4] = {v.x, v.y, v.z, v.w};
#pragma unroll
      for (int j = 0; j < 4; ++j) {
        int e = 4 * q + j;  // compile-time after unroll
        float p = vv[j];
        float lp = __logf(fmaxf(p, 1e-10f));
        if (e < 10) {
          u0 -= p * lp;
          if (p > m0) { m0 = p; am0 = e; }      // strict > keeps first max
        } else {
          u1 -= p * lp;
          if (p > m1) { m1 = p; am1 = e - 10; }
        }
      }
    }
    mnA = fminf(mnA, fminf(u0, u1));
    mxA = fmaxf(mxA, fmaxf(u0, u1));

    // pack acc into sign bit (unc >= 0; sign set == inaccurate)
    unsigned s0 = __float_as_uint(u0) | ((am0 == label0) ? 0u : 0x80000000u);
    unsigned s1 = __float_as_uint(u1) | ((am1 == label0) ? 0u : 0x80000000u);
    f2_t o;
    o.x = __uint_as_float(s0);
    o.y = __uint_as_float(s1);
    __builtin_nontemporal_store(o, (f2_t*)&us2[(size_t)c * 64 + lane]);
  }

  // per-wave reduce + spread-slot atomics.
  float ce = waveSum(ceA), fo = waveSum(foA);
  float mn = waveMin(mnA), mx = waveMax(mxA);
  if (lane == 0) {
    int slot = gw & 63;
    atomicAdd(&ceSlots[slot], ce);
    atomicAdd(&focalSlots[slot], fo);
    atomicMax(&uminInvSlots[slot], ~__float_as_uint(mn));  // min via ~bits
    atomicMax(&umaxSlots[slot], __float_as_uint(mx));
  }
}

// ---------------- pass 2: 22-bin x 4-category histogram. grid 1024 = exactly
// 4 iterations/thread. NO done-counter / fused finale (round-3 regression:
// serialized same-address cross-XCD atomics). NT load on us. UNCHANGED
// (single-variable discipline).
__global__ __launch_bounds__(256, 4) void pass2(
    const float4* __restrict__ us4, int n4,
    const unsigned* __restrict__ uminInvSlots, const unsigned* __restrict__ umaxSlots,
    float* __restrict__ ghist) {
  __shared__ float hist[88 * 64];  // [row][lane], 22528 B
  __shared__ float smm[2];
  const int tid = threadIdx.x, lane = tid & 63;
  for (int i = tid; i < 88 * 64; i += 256) hist[i] = 0.f;
  if (tid < 64) {
    unsigned mnInv = waveMaxU(uminInvSlots[tid]);
    unsigned mxb = waveMaxU(umaxSlots[tid]);
    if (tid == 0) { smm[0] = __uint_as_float(~mnInv); smm[1] = __uint_as_float(mxb); }
  }
  __syncthreads();
  const float umin = smm[0], delta = smm[1] - smm[0];
  float th[21];
#pragma unroll
  for (int k = 0; k < 21; ++k) th[k] = fmaf(0.05f * (float)k, delta, umin);

  const int stride = gridDim.x * 256;
  for (int i = blockIdx.x * 256 + tid; i < n4; i += stride) {
    f4_t v = __builtin_nontemporal_load((const f4_t*)us4 + i);
    float vv[4] = {v.x, v.y, v.z, v.w};
#pragma unroll
    for (int q = 0; q < 4; ++q) {
      unsigned b = __float_as_uint(vv[q]);
      int rb = (b >> 31) ? 44 : 0;  // acc rows 0..43, inacc rows 44..87
      float u = __uint_as_float(b & 0x7fffffffu);
      float e = u * 0.4342944819f;  // u / ln(10)
      float lnum = __logf(e * 0.9f);
      float lden = __logf(fmaxf((1.f - e) * 0.1f, 1e-10f));
      float x = fmaxf(lnum - lden, -23.0258509f) * 100.f;
      float s = __builtin_amdgcn_rcpf(1.f + __expf(-x));                   // sigmoid
      float t = 1.f - 2.f * __builtin_amdgcn_rcpf(__expf(2.f * u) + 1.f);  // tanh
      float wc = (1.f - s) * (1.f - t), wu = s * t;
      int j = 0;  // j = #{k: u > th_k}; le[k] <=> k >= j
#pragma unroll
      for (int k = 0; k < 21; ++k) j += (u > th[k]) ? 1 : 0;
      atomicAdd(&hist[(rb + j) * 64 + lane], wc);        // ds_add_f32
      atomicAdd(&hist[(rb + 22 + j) * 64 + lane], wu);
    }
  }
  __syncthreads();
  // tree-reduce 64 columns per row
#pragma unroll
  for (int st = 32; st >= 1; st >>= 1) {
    for (int idx = tid; idx < 88 * st; idx += 256) {
      int r = idx / st, c = idx - r * st;
      hist[r * 64 + c] += hist[r * 64 + c + st];
    }
    __syncthreads();
  }
  int slot = blockIdx.x & 63;
  for (int r = tid; r < 88; r += 256)
    atomicAdd(&ghist[slot * 88 + r], hist[r * 64]);
}

// ---------------- pass 3: reduce 64 slot-copies + scalar slots, emit outputs
__global__ __launch_bounds__(256) void pass3(
    const float* __restrict__ ghist,
    const float* __restrict__ ceSlots, const float* __restrict__ focalSlots,
    float* __restrict__ out, float invN) {
  __shared__ float hr[96];
  __shared__ float scf[2];
  int tid = threadIdx.x;
  if (tid < 88) {
    float s = 0.f;
    for (int q = 0; q < 64; ++q) s += ghist[q * 88 + tid];  // coalesced across tid
    hr[tid] = s;
  }
  if (tid >= 128 && tid < 192) {
    int l = tid - 128;
    float ce = waveSum(ceSlots[l]);
    float fo = waveSum(focalSlots[l]);
    if (l == 0) { scf[0] = ce; scf[1] = fo; }
  }
  __syncthreads();
  if (tid == 0) {
    // Running sums straight from LDS (low-VGPR finale).
    float totAU = 0.f, totIU = 0.f;
    for (int j = 0; j < 22; ++j) { totAU += hr[22 + j]; totIU += hr[66 + j]; }
    float n_ac = 0.f, n_ic = 0.f, n_au = totAU, n_iu = totIU;
    float auc = 0.f, prev = 0.f;
    for (int k = 0; k < 21; ++k) {
      n_ac += hr[k]; n_ic += hr[44 + k];
      n_au -= hr[22 + k]; n_iu -= hr[66 + k];
      float avu = (n_ac + n_iu) / (n_ac + n_au + n_ic + n_iu + 1e-10f);
      if (k > 0) auc += (avu + prev) * 0.5f * 0.05f;
      prev = avu;
    }
    out[0] = -logf(fmaxf(auc, 1e-10f)) + scf[1] * invN;
    out[1] = scf[0] * invN;
  }
}

extern "C" void kernel_launch(void* const* d_in, const int* in_sizes, int n_in,
                              void* d_out, int out_size, void* d_ws, size_t ws_size,
                              hipStream_t stream) {
  const float* probs = (const float*)d_in[0];
  const float* y = (const float*)d_in[1];
  float* out = (float*)d_out;
  const int N = in_sizes[0] / C;

  // ws layout (floats): [0,64) uminInv slots, [64,128) umax slots,
  // [128,192) ce slots, [192,256) focal slots, [256,5888) ghist[64][88],
  // [5888, 5888+N) us
  float* wsf = (float*)d_ws;
  unsigned* uminInvSlots = (unsigned*)wsf;
  unsigned* umaxSlots = (unsigned*)(wsf + 64);
  float* ceSlots = wsf + 128;
  float* focalSlots = wsf + 192;
  float* ghist = wsf + 256;
  float* us = wsf + 5888;

  hipMemsetAsync(d_ws, 0, 5888 * sizeof(float), stream);  // accumulators -> 0

  const int nchunks = N / CHUNK_ROWS;  // 4194304/128 = 32768
  float invN = 1.0f / (float)N;

  // 8192 single-wave blocks = 32 blocks/CU (LDS 5120 B x 32 = 160 KiB),
  // 4 chunks/wave.
  pass1<<<8192, 64, 0, stream>>>((const float4*)probs, (const float4*)y,
                                 (float2*)us, uminInvSlots, umaxSlots,
                                 ceSlots, focalSlots, nchunks);
  pass2<<<1024, 256, 0, stream>>>((const float4*)us, N / 4, uminInvSlots,
                                  umaxSlots, ghist);
  pass3<<<1, 256, 0, stream>>>(ghist, ceSlots, focalSlots, out, invN);
}